// Round 1
// baseline (10650.633 us; speedup 1.0000x reference)
//
#include <hip/hip_runtime.h>
#include <cstdint>

#define NPTS 32768
#define DIM  256
#define NK   128
#define NITER 100

typedef __attribute__((ext_vector_type(8))) short s8v;   // 8 bf16 in 4 VGPRs
typedef __attribute__((ext_vector_type(4))) float f4v;   // MFMA accumulator

__device__ __forceinline__ unsigned short f2bf(float f) {
  unsigned u = __float_as_uint(f);
  u += 0x7fffu + ((u >> 16) & 1u);      // RTNE
  return (unsigned short)(u >> 16);
}
__device__ __forceinline__ float bf2f(unsigned short b) {
  return __uint_as_float(((unsigned)b) << 16);
}

// ---------------- init: c0 = x[init_idx], cn from bf16-rounded c ----------------
__global__ void init_c_kernel(const float* __restrict__ x, const int* __restrict__ idx,
                              float* __restrict__ c, float* __restrict__ cn) {
  int k = blockIdx.x, d = threadIdx.x;
  float v = x[idx[k] * DIM + d];
  c[k * DIM + d] = v;
  float mb = bf2f(f2bf(v));
  __shared__ float red[256];
  red[d] = mb * mb;
  __syncthreads();
  for (int s = 128; s > 0; s >>= 1) { if (d < s) red[d] += red[d + s]; __syncthreads(); }
  if (d == 0) cn[k] = red[0];
}

// ---------------- fused GEMM (bf16 MFMA) + epilogue ----------------
// MODE 0: ids[p] = argmin_k (cn[k] - 2 * x_p . c_k)
// MODE 1: loss = mean_p ( logsumexp_k(x_p . c_k) - (x_p . c_{ids[p]}) ), atomicAdd into out
template <int MODE>
__global__ __launch_bounds__(256) void gemm_epi_kernel(
    const float* __restrict__ x, const float* __restrict__ c,
    const float* __restrict__ cn, int* __restrict__ ids, float* __restrict__ out) {
  // LDS: swizzled bf16 tiles, 128 rows x 512B each
  __shared__ s8v xs[4096];     // 64 KB
  __shared__ s8v cs[4096];     // 64 KB
  __shared__ float cns[NK];
  __shared__ float redd[NK * 2];
  __shared__ int   redk[NK * 2];
  __shared__ float gmaxs[NK];
  __shared__ float labvs[NK];
  __shared__ int   labis[NK];

  const int t    = threadIdx.x;
  const int lane = t & 63;
  const int w    = t >> 6;
  const int wr   = w >> 1, wc = w & 1;          // 2x2 wave grid, 64x64 tile each
  const int g    = lane >> 4, lr = lane & 15;
  const int pbase = blockIdx.x * 128;

  // ---- stage x tile: 128 rows x 256 f32 -> bf16, XOR-swizzled (row&7)<<4 ----
  {
    const float4* xg = (const float4*)(x + pbase * DIM);
    char* xsb = (char*)xs;
    for (int rr = 0; rr < 16; ++rr) {
      int g16 = rr * 256 + t;                   // 16B granule index [0,4096)
      int row = g16 >> 5;                       // 32 granules per 512B row
      float4 fa = xg[g16 * 2];
      float4 fb = xg[g16 * 2 + 1];
      s8v v;
      v[0] = (short)f2bf(fa.x); v[1] = (short)f2bf(fa.y);
      v[2] = (short)f2bf(fa.z); v[3] = (short)f2bf(fa.w);
      v[4] = (short)f2bf(fb.x); v[5] = (short)f2bf(fb.y);
      v[6] = (short)f2bf(fb.z); v[7] = (short)f2bf(fb.w);
      int byte = (g16 * 16) ^ ((row & 7) << 4);
      *(s8v*)(xsb + byte) = v;
    }
    const float4* cg = (const float4*)c;
    char* csb = (char*)cs;
    for (int rr = 0; rr < 16; ++rr) {
      int g16 = rr * 256 + t;
      int row = g16 >> 5;
      float4 fa = cg[g16 * 2];
      float4 fb = cg[g16 * 2 + 1];
      s8v v;
      v[0] = (short)f2bf(fa.x); v[1] = (short)f2bf(fa.y);
      v[2] = (short)f2bf(fa.z); v[3] = (short)f2bf(fa.w);
      v[4] = (short)f2bf(fb.x); v[5] = (short)f2bf(fb.y);
      v[6] = (short)f2bf(fb.z); v[7] = (short)f2bf(fb.w);
      int byte = (g16 * 16) ^ ((row & 7) << 4);
      *(s8v*)(csb + byte) = v;
    }
    if (t < NK) cns[t] = cn[t];
  }
  __syncthreads();

  // ---- K-loop: 8 steps of K=32, 4x4 MFMA frags per wave ----
  f4v acc[4][4];
  const f4v zero = {0.f, 0.f, 0.f, 0.f};
#pragma unroll
  for (int i = 0; i < 4; ++i)
#pragma unroll
    for (int j = 0; j < 4; ++j) acc[i][j] = zero;

  const char* xsb = (const char*)xs;
  const char* csb = (const char*)cs;
  int a_lin[4], b_lin[4];
#pragma unroll
  for (int i = 0; i < 4; ++i) a_lin[i] = (wr * 64 + i * 16 + lr) * 512 + g * 16;
#pragma unroll
  for (int j = 0; j < 4; ++j) b_lin[j] = (wc * 64 + j * 16 + lr) * 512 + g * 16;
  const int swz = (lane & 7) << 4;   // row&7 == lane&7 for all frag rows (bases %8==0)

#pragma unroll
  for (int kk = 0; kk < 8; ++kk) {
    s8v a[4], b[4];
#pragma unroll
    for (int i = 0; i < 4; ++i) a[i] = *(const s8v*)(xsb + ((a_lin[i] + kk * 64) ^ swz));
#pragma unroll
    for (int j = 0; j < 4; ++j) b[j] = *(const s8v*)(csb + ((b_lin[j] + kk * 64) ^ swz));
#pragma unroll
    for (int i = 0; i < 4; ++i)
#pragma unroll
      for (int j = 0; j < 4; ++j)
        acc[i][j] = __builtin_amdgcn_mfma_f32_16x16x32_bf16(a[i], b[j], acc[i][j], 0, 0, 0);
  }

  // D layout: col = lane&15, row(in 16x16) = (lane>>4)*4 + reg
  if (MODE == 0) {
#pragma unroll
    for (int i = 0; i < 4; ++i) {
#pragma unroll
      for (int r = 0; r < 4; ++r) {
        int prow = wr * 64 + i * 16 + g * 4 + r;
        float bd = 1e30f; int bk = 0;
#pragma unroll
        for (int j = 0; j < 4; ++j) {
          int col = wc * 64 + j * 16 + lr;
          float s = cns[col] - 2.f * acc[i][j][r];
          if (s < bd || (s == bd && col < bk)) { bd = s; bk = col; }
        }
#pragma unroll
        for (int msk = 1; msk < 16; msk <<= 1) {
          float od = __shfl_xor(bd, msk, 64);
          int   ok = __shfl_xor(bk, msk, 64);
          if (od < bd || (od == bd && ok < bk)) { bd = od; bk = ok; }
        }
        if (lr == 0) { redd[prow * 2 + wc] = bd; redk[prow * 2 + wc] = bk; }
      }
    }
    __syncthreads();
    if (t < NK) {
      float d0 = redd[t * 2], d1 = redd[t * 2 + 1];
      int k0 = redk[t * 2], k1 = redk[t * 2 + 1];
      ids[pbase + t] = (d1 < d0 || (d1 == d0 && k1 < k0)) ? k1 : k0;
    }
  }

  if (MODE == 1) {
#pragma unroll
    for (int i = 0; i < 4; ++i) {
#pragma unroll
      for (int r = 0; r < 4; ++r) {
        int prow = wr * 64 + i * 16 + g * 4 + r;
        float m = -1e30f;
#pragma unroll
        for (int j = 0; j < 4; ++j) m = fmaxf(m, acc[i][j][r]);
#pragma unroll
        for (int msk = 1; msk < 16; msk <<= 1) m = fmaxf(m, __shfl_xor(m, msk, 64));
        if (lr == 0) redd[prow * 2 + wc] = m;
      }
    }
    __syncthreads();
    if (t < NK) {
      gmaxs[t] = fmaxf(redd[t * 2], redd[t * 2 + 1]);
      labis[t] = ids[pbase + t];
    }
    __syncthreads();
#pragma unroll
    for (int i = 0; i < 4; ++i) {
#pragma unroll
      for (int r = 0; r < 4; ++r) {
        int prow = wr * 64 + i * 16 + g * 4 + r;
        float m = gmaxs[prow];
        int lab = labis[prow];
        float s = 0.f;
#pragma unroll
        for (int j = 0; j < 4; ++j) {
          int col = wc * 64 + j * 16 + lr;
          float v = acc[i][j][r];
          s += expf(v - m);
          if (col == lab) labvs[prow] = v;
        }
#pragma unroll
        for (int msk = 1; msk < 16; msk <<= 1) s += __shfl_xor(s, msk, 64);
        if (lr == 0) redd[prow * 2 + wc] = s;
      }
    }
    __syncthreads();
    if (t < NK) {
      float se  = redd[t * 2] + redd[t * 2 + 1];
      float lse = gmaxs[t] + logf(se);
      gmaxs[t] = lse - labvs[t];
    }
    __syncthreads();
    if (t == 0) {
      float tot = 0.f;
      for (int q = 0; q < NK; ++q) tot += gmaxs[q];
      atomicAdd(out, tot * (1.0f / (float)NPTS));
    }
  }
}

// ---------------- update: LDS-atomic partial segment sums ----------------
// grid 128 = 32 point-chunks x 4 D-chunks; block 256 = 4 waves (1 point/wave/step)
__global__ void update_partial_kernel(const float* __restrict__ x, const int* __restrict__ ids,
                                      float* __restrict__ psum, float* __restrict__ pcnt) {
  __shared__ float ls[NK * 64];
  __shared__ float lc[NK];
  const int t = threadIdx.x;
  const int pc = blockIdx.x & 31, dc = blockIdx.x >> 5;
  for (int r = t; r < NK * 64; r += 256) ls[r] = 0.f;
  if (t < NK) lc[t] = 0.f;
  __syncthreads();
  const int sub = t >> 6, dl = t & 63;
  const int dcol = dc * 64 + dl;
  for (int s = 0; s < 256; ++s) {
    int p = pc * 1024 + s * 4 + sub;
    int id = ids[p];
    float v = x[p * DIM + dcol];
    atomicAdd(&ls[id * 64 + dl], v);
    if (dc == 0 && dl == 0) atomicAdd(&lc[id], 1.f);
  }
  __syncthreads();
  for (int r = 0; r < 32; ++r) {
    int k = r * 4 + sub;
    psum[(pc * NK + k) * DIM + dc * 64 + dl] = ls[k * 64 + dl];
  }
  if (dc == 0 && t < NK) pcnt[pc * NK + t] = lc[t];
}

// ---------------- reduce partials -> means, cn from bf16-rounded means ----------------
__global__ void reduce_update_kernel(const float* __restrict__ psum, const float* __restrict__ pcnt,
                                     float* __restrict__ c, float* __restrict__ cn) {
  int k = blockIdx.x, d = threadIdx.x;
  float s = 0.f;
  for (int pc = 0; pc < 32; ++pc) s += psum[(pc * NK + k) * DIM + d];
  float cntv = 0.f;
  for (int pc = 0; pc < 32; ++pc) cntv += pcnt[pc * NK + k];
  float mean = s / cntv;                 // NaN for empty cluster, like reference
  c[k * DIM + d] = mean;
  float mb = bf2f(f2bf(mean));           // consistency with bf16 GEMM staging
  __shared__ float red[256];
  red[d] = mb * mb;
  __syncthreads();
  for (int st = 128; st > 0; st >>= 1) { if (d < st) red[d] += red[d + st]; __syncthreads(); }
  if (d == 0) cn[k] = red[0];
}

extern "C" void kernel_launch(void* const* d_in, const int* in_sizes, int n_in,
                              void* d_out, int out_size, void* d_ws, size_t ws_size,
                              hipStream_t stream) {
  const float* x        = (const float*)d_in[0];
  const int*   init_idx = (const int*)d_in[1];
  float* out = (float*)d_out;
  char* ws = (char*)d_ws;

  float* c    = (float*)(ws);                       // 128*256*4   = 131072
  float* cn   = (float*)(ws + 131072);              // 128*4       = 512
  int*   ids  = (int*)(ws + 131584);                // 32768*4     = 131072
  float* psum = (float*)(ws + 262656);              // 32*128*256*4= 4194304
  float* pcnt = (float*)(ws + 262656 + 32 * NK * DIM * 4);  // 32*128*4

  hipMemsetAsync(out, 0, sizeof(float), stream);
  init_c_kernel<<<NK, 256, 0, stream>>>(x, init_idx, c, cn);
  for (int it = 0; it < NITER; ++it) {
    gemm_epi_kernel<0><<<NPTS / 128, 256, 0, stream>>>(x, c, cn, ids, out);
    update_partial_kernel<<<128, 256, 0, stream>>>(x, ids, psum, pcnt);
    reduce_update_kernel<<<NK, 256, 0, stream>>>(psum, pcnt, c, cn);
  }
  gemm_epi_kernel<1><<<NPTS / 128, 256, 0, stream>>>(x, c, cn, ids, out);
}

// Round 2
// 8280.462 us; speedup vs baseline: 1.2862x; 1.2862x over previous
//
#include <hip/hip_runtime.h>
#include <cstdint>

#define NPTS 32768
#define DIM  256
#define NK   128
#define NITER 100

typedef __attribute__((ext_vector_type(8))) short s8v;   // 8 bf16 in 4 VGPRs
typedef __attribute__((ext_vector_type(4))) float f4v;   // MFMA accumulator

__device__ __forceinline__ unsigned short f2bf(float f) {
  unsigned u = __float_as_uint(f);
  u += 0x7fffu + ((u >> 16) & 1u);      // RTNE
  return (unsigned short)(u >> 16);
}
__device__ __forceinline__ float bf2f(unsigned short b) {
  return __uint_as_float(((unsigned)b) << 16);
}

// ---------------- prep: x -> bf16 hi/lo row-major images (done ONCE) ----------------
__global__ __launch_bounds__(256) void prep_x_kernel(const float* __restrict__ x,
    unsigned short* __restrict__ xh, unsigned short* __restrict__ xl) {
  for (int i = 0; i < 16; ++i) {
    int g = blockIdx.x * 4096 + i * 256 + threadIdx.x;   // 16B granule = 8 elems
    const float4* src = (const float4*)x + g * 2;
    float4 a = src[0], b = src[1];
    float vv[8] = {a.x, a.y, a.z, a.w, b.x, b.y, b.z, b.w};
    s8v vh, vl;
#pragma unroll
    for (int j = 0; j < 8; ++j) {
      unsigned short h = f2bf(vv[j]);
      vh[j] = (short)h;
      vl[j] = (short)f2bf(vv[j] - bf2f(h));
    }
    ((s8v*)xh)[g] = vh;
    ((s8v*)xl)[g] = vl;
  }
}

// ---------------- init: c0 = x[init_idx] -> hi/lo images + cn ----------------
__global__ void init_c_kernel(const float* __restrict__ x, const int* __restrict__ idx,
                              unsigned short* __restrict__ chi, unsigned short* __restrict__ clo,
                              float* __restrict__ cn) {
  int k = blockIdx.x, d = threadIdx.x;
  float v = x[idx[k] * DIM + d];
  unsigned short h = f2bf(v);
  unsigned short l = f2bf(v - bf2f(h));
  chi[k * DIM + d] = h;
  clo[k * DIM + d] = l;
  float eff = bf2f(h) + bf2f(l);
  __shared__ float red[256];
  red[d] = eff * eff;
  __syncthreads();
  for (int s = 128; s > 0; s >>= 1) { if (d < s) red[d] += red[d + s]; __syncthreads(); }
  if (d == 0) cn[k] = red[0];
}

// ---------------- fused GEMM (3-pass hi/lo bf16 MFMA) + epilogue ----------------
template <int MODE>
__global__ __launch_bounds__(256) void gemm_epi_kernel(
    const unsigned short* __restrict__ xh, const unsigned short* __restrict__ xl,
    const unsigned short* __restrict__ chi, const unsigned short* __restrict__ clo,
    const float* __restrict__ cn, int* __restrict__ ids, float* __restrict__ out) {
  __shared__ s8v bufs[4][2048];           // XH, XL, CH, CL half-D tiles, 32 KB each
  __shared__ float cns[NK];
  __shared__ float redd[NK * 2];
  __shared__ int   redk[NK * 2];
  __shared__ float gmaxs[NK];
  __shared__ float labvs[NK];
  __shared__ int   labis[NK];

  const int t    = threadIdx.x;
  const int lane = t & 63;
  const int w    = t >> 6;
  const int wr   = w >> 1, wc = w & 1;    // 2x2 wave grid, 64x64 tile each
  const int g    = lane >> 4, lr = lane & 15;
  const int pbase = blockIdx.x * 128;

  if (t < NK) cns[t] = cn[t];

  f4v acc[4][4];
  const f4v zero = {0.f, 0.f, 0.f, 0.f};
#pragma unroll
  for (int i = 0; i < 4; ++i)
#pragma unroll
    for (int j = 0; j < 4; ++j) acc[i][j] = zero;

  const int swz = (lr & 7) << 4;
  int a_off[4], b_off[4];
#pragma unroll
  for (int i = 0; i < 4; ++i) a_off[i] = (wr * 64 + i * 16 + lr) * 256 + g * 16;
#pragma unroll
  for (int j = 0; j < 4; ++j) b_off[j] = (wc * 64 + j * 16 + lr) * 256 + g * 16;

  const unsigned short* srcs[4];
  srcs[0] = xh + pbase * DIM;
  srcs[1] = xl + pbase * DIM;
  srcs[2] = chi;
  srcs[3] = clo;

  for (int h = 0; h < 2; ++h) {           // two D-halves of 128
    __syncthreads();
#pragma unroll
    for (int b = 0; b < 4; ++b) {
      const char* sp = (const char*)srcs[b];
      char* dp = (char*)bufs[b];
#pragma unroll
      for (int i = 0; i < 8; ++i) {
        int gg = i * 256 + t;             // granule within 32KB buffer
        int row = gg >> 4, whb = (gg & 15) * 16;
        s8v v = *(const s8v*)(sp + row * 512 + h * 256 + whb);
        *(s8v*)(dp + ((gg * 16) ^ ((row & 7) << 4))) = v;
      }
    }
    __syncthreads();
#pragma unroll
    for (int kk = 0; kk < 4; ++kk) {      // K=128 per half, 4 steps of 32
      s8v ah[4], al[4], bh[4], bl[4];
#pragma unroll
      for (int i = 0; i < 4; ++i) {
        int o = (a_off[i] + kk * 64) ^ swz;
        ah[i] = *(const s8v*)((const char*)bufs[0] + o);
        al[i] = *(const s8v*)((const char*)bufs[1] + o);
      }
#pragma unroll
      for (int j = 0; j < 4; ++j) {
        int o = (b_off[j] + kk * 64) ^ swz;
        bh[j] = *(const s8v*)((const char*)bufs[2] + o);
        bl[j] = *(const s8v*)((const char*)bufs[3] + o);
      }
#pragma unroll
      for (int i = 0; i < 4; ++i)
#pragma unroll
        for (int j = 0; j < 4; ++j) {
          acc[i][j] = __builtin_amdgcn_mfma_f32_16x16x32_bf16(ah[i], bh[j], acc[i][j], 0, 0, 0);
          acc[i][j] = __builtin_amdgcn_mfma_f32_16x16x32_bf16(ah[i], bl[j], acc[i][j], 0, 0, 0);
          acc[i][j] = __builtin_amdgcn_mfma_f32_16x16x32_bf16(al[i], bh[j], acc[i][j], 0, 0, 0);
        }
    }
  }

  // D layout: col = lane&15, row(in 16x16) = (lane>>4)*4 + reg
  if (MODE == 0) {
#pragma unroll
    for (int i = 0; i < 4; ++i) {
#pragma unroll
      for (int r = 0; r < 4; ++r) {
        int prow = wr * 64 + i * 16 + g * 4 + r;
        float bd = 1e30f; int bk = 0;
#pragma unroll
        for (int j = 0; j < 4; ++j) {
          int col = wc * 64 + j * 16 + lr;
          float s = cns[col] - 2.f * acc[i][j][r];
          if (s < bd || (s == bd && col < bk)) { bd = s; bk = col; }
        }
#pragma unroll
        for (int msk = 1; msk < 16; msk <<= 1) {
          float od = __shfl_xor(bd, msk, 64);
          int   ok = __shfl_xor(bk, msk, 64);
          if (od < bd || (od == bd && ok < bk)) { bd = od; bk = ok; }
        }
        if (lr == 0) { redd[prow * 2 + wc] = bd; redk[prow * 2 + wc] = bk; }
      }
    }
    __syncthreads();
    if (t < NK) {
      float d0 = redd[t * 2], d1 = redd[t * 2 + 1];
      int k0 = redk[t * 2], k1 = redk[t * 2 + 1];
      ids[pbase + t] = (d1 < d0 || (d1 == d0 && k1 < k0)) ? k1 : k0;
    }
  }

  if (MODE == 1) {
#pragma unroll
    for (int i = 0; i < 4; ++i) {
#pragma unroll
      for (int r = 0; r < 4; ++r) {
        int prow = wr * 64 + i * 16 + g * 4 + r;
        float m = -1e30f;
#pragma unroll
        for (int j = 0; j < 4; ++j) m = fmaxf(m, acc[i][j][r]);
#pragma unroll
        for (int msk = 1; msk < 16; msk <<= 1) m = fmaxf(m, __shfl_xor(m, msk, 64));
        if (lr == 0) redd[prow * 2 + wc] = m;
      }
    }
    __syncthreads();
    if (t < NK) {
      gmaxs[t] = fmaxf(redd[t * 2], redd[t * 2 + 1]);
      labis[t] = ids[pbase + t];
    }
    __syncthreads();
#pragma unroll
    for (int i = 0; i < 4; ++i) {
#pragma unroll
      for (int r = 0; r < 4; ++r) {
        int prow = wr * 64 + i * 16 + g * 4 + r;
        float m = gmaxs[prow];
        int lab = labis[prow];
        float s = 0.f;
#pragma unroll
        for (int j = 0; j < 4; ++j) {
          int col = wc * 64 + j * 16 + lr;
          float v = acc[i][j][r];
          s += expf(v - m);
          if (col == lab) labvs[prow] = v;
        }
#pragma unroll
        for (int msk = 1; msk < 16; msk <<= 1) s += __shfl_xor(s, msk, 64);
        if (lr == 0) redd[prow * 2 + wc] = s;
      }
    }
    __syncthreads();
    if (t < NK) {
      float se  = redd[t * 2] + redd[t * 2 + 1];
      float lse = gmaxs[t] + logf(se);
      gmaxs[t] = lse - labvs[t];
    }
    __syncthreads();
    if (t == 0) {
      float tot = 0.f;
      for (int q = 0; q < NK; ++q) tot += gmaxs[q];
      atomicAdd(out, tot * (1.0f / (float)NPTS));
    }
  }
}

// ---------------- update: LDS-atomic partial segment sums ----------------
// grid 256 = 32 point-chunks x 8 D-chunks(32 dims); block 256 threads
__global__ __launch_bounds__(256) void update_partial_kernel(
    const float* __restrict__ x, const int* __restrict__ ids,
    float* __restrict__ psum, float* __restrict__ pcnt) {
  __shared__ float ls[NK * 32];
  __shared__ float lc[NK];
  __shared__ int idsl[1024];
  const int t = threadIdx.x;
  const int pc = blockIdx.x & 31, dc = blockIdx.x >> 5;
  for (int r = t; r < NK * 32; r += 256) ls[r] = 0.f;
  if (t < NK) lc[t] = 0.f;
  for (int r = t; r < 1024; r += 256) idsl[r] = ids[pc * 1024 + r];
  __syncthreads();
  const int sub = t >> 5, dl = t & 31;
  const int dcol = dc * 32 + dl;
  for (int s = 0; s < 128; ++s) {
    int pl = s * 8 + sub;
    int id = idsl[pl];
    float v = x[(pc * 1024 + pl) * DIM + dcol];
    atomicAdd(&ls[id * 32 + dl], v);
    if (dc == 0 && dl == 0) atomicAdd(&lc[id], 1.f);
  }
  __syncthreads();
  for (int r = 0; r < 16; ++r) {
    int idx = r * 256 + t;
    int k = idx >> 5, d2 = idx & 31;
    psum[(pc * NK + k) * DIM + dc * 32 + d2] = ls[k * 32 + d2];
  }
  if (dc == 0 && t < NK) pcnt[pc * NK + t] = lc[t];
}

// ---------------- reduce partials -> means -> hi/lo images + cn ----------------
__global__ void reduce_update_kernel(const float* __restrict__ psum, const float* __restrict__ pcnt,
                                     unsigned short* __restrict__ chi, unsigned short* __restrict__ clo,
                                     float* __restrict__ cn) {
  int k = blockIdx.x, d = threadIdx.x;
  float s = 0.f;
  for (int pc = 0; pc < 32; ++pc) s += psum[(pc * NK + k) * DIM + d];
  float cntv = 0.f;
  for (int pc = 0; pc < 32; ++pc) cntv += pcnt[pc * NK + k];
  float mean = s / cntv;                 // NaN for empty cluster, like reference
  unsigned short h = f2bf(mean);
  unsigned short l = f2bf(mean - bf2f(h));
  chi[k * DIM + d] = h;
  clo[k * DIM + d] = l;
  float eff = bf2f(h) + bf2f(l);
  __shared__ float red[256];
  red[d] = eff * eff;
  __syncthreads();
  for (int st = 128; st > 0; st >>= 1) { if (d < st) red[d] += red[d + st]; __syncthreads(); }
  if (d == 0) cn[k] = red[0];
}

extern "C" void kernel_launch(void* const* d_in, const int* in_sizes, int n_in,
                              void* d_out, int out_size, void* d_ws, size_t ws_size,
                              hipStream_t stream) {
  const float* x        = (const float*)d_in[0];
  const int*   init_idx = (const int*)d_in[1];
  float* out = (float*)d_out;
  char* ws = (char*)d_ws;

  // ws layout (bytes):
  unsigned short* xh  = (unsigned short*)(ws);                   // 16777216
  unsigned short* xl  = (unsigned short*)(ws + 16777216);        // 16777216
  unsigned short* chi = (unsigned short*)(ws + 33554432);        // 65536
  unsigned short* clo = (unsigned short*)(ws + 33619968);        // 65536
  float* cn   = (float*)(ws + 33685504);                         // 512
  int*   ids  = (int*)(ws + 33686016);                           // 131072
  float* psum = (float*)(ws + 33817088);                         // 4194304
  float* pcnt = (float*)(ws + 38011392);                         // 16384

  hipMemsetAsync(out, 0, sizeof(float), stream);
  prep_x_kernel<<<256, 256, 0, stream>>>(x, xh, xl);
  init_c_kernel<<<NK, 256, 0, stream>>>(x, init_idx, chi, clo, cn);
  for (int it = 0; it < NITER; ++it) {
    gemm_epi_kernel<0><<<NPTS / 128, 256, 0, stream>>>(xh, xl, chi, clo, cn, ids, out);
    update_partial_kernel<<<256, 256, 0, stream>>>(x, ids, psum, pcnt);
    reduce_update_kernel<<<NK, 256, 0, stream>>>(psum, pcnt, chi, clo, cn);
  }
  gemm_epi_kernel<1><<<NPTS / 128, 256, 0, stream>>>(xh, xl, chi, clo, cn, ids, out);
}